// Round 1
// baseline (777.126 us; speedup 1.0000x reference)
//
#include <hip/hip_runtime.h>
#include <cmath>

typedef __bf16 bf16;
typedef short bf16x8 __attribute__((ext_vector_type(8)));   // MFMA A/B fragment (bf16 bit patterns)
typedef __bf16 bf16v8 __attribute__((ext_vector_type(8)));  // arithmetic bf16 vector
typedef __bf16 bf16v4 __attribute__((ext_vector_type(4)));
typedef float f32x4 __attribute__((ext_vector_type(4)));
typedef unsigned short u16x8 __attribute__((ext_vector_type(8)));

// ---------------------------------------------------------------------------
// fp32 -> bf16 elementwise convert (optionally scaled). n multiple of 4.
__global__ void k_cvt(const float* __restrict__ in, bf16* __restrict__ out,
                      int n, float scale) {
    int i = (blockIdx.x * 256 + threadIdx.x) * 4;
    if (i >= n) return;
    float4 v = *(const float4*)(in + i);
    bf16v4 o;
    o[0] = (bf16)(v.x * scale);
    o[1] = (bf16)(v.y * scale);
    o[2] = (bf16)(v.z * scale);
    o[3] = (bf16)(v.w * scale);
    *(bf16v4*)(out + i) = o;
}

// ---------------------------------------------------------------------------
// Weight convert + transpose: w[K=2048][N=2048] f32 -> wt[N][K] bf16 (scaled).
__global__ void k_wt(const float* __restrict__ w, bf16* __restrict__ wt, float scale) {
    __shared__ float tile[32][33];
    const int tid = threadIdx.x;
    const int tx = tid & 31, ty = tid >> 5;  // 32 x 8
    const int k0 = blockIdx.x * 32, n0 = blockIdx.y * 32;
#pragma unroll
    for (int i = 0; i < 4; i++) {
        int kk = ty + i * 8;
        tile[kk][tx] = w[(size_t)(k0 + kk) * 2048 + n0 + tx];
    }
    __syncthreads();
#pragma unroll
    for (int i = 0; i < 4; i++) {
        int nn = ty + i * 8;
        wt[(size_t)(n0 + nn) * 2048 + k0 + tx] = (bf16)(tile[tx][nn] * scale);
    }
}

// ---------------------------------------------------------------------------
// bf16 GEMM: C[M][N] = A[M][K] * Bt[N][K]^T.  128x128 tile, 4 waves (2x2),
// each wave 64x64 via 4x4 grid of 16x16x32 MFMA tiles. BK=32.
template <int F32OUT>
__global__ __launch_bounds__(256) void k_gemm_bt(
    const bf16* __restrict__ A, const bf16* __restrict__ Bt,
    bf16* __restrict__ Cb, float* __restrict__ Cf, int M, int N, int K) {
    constexpr int LS = 40;  // padded LDS row stride (elements), multiple of 8
    __shared__ __align__(16) bf16 sA[128 * LS];
    __shared__ __align__(16) bf16 sB[128 * LS];
    const int tid = threadIdx.x;
    const int wave = tid >> 6, lane = tid & 63;
    const int quad = lane >> 4, l15 = lane & 15;
    const int wm = (wave >> 1) * 64, wn = (wave & 1) * 64;
    const int m0 = blockIdx.x * 128, n0 = blockIdx.y * 128;

    f32x4 acc[4][4];
#pragma unroll
    for (int a = 0; a < 4; a++)
#pragma unroll
        for (int c = 0; c < 4; c++)
#pragma unroll
            for (int r = 0; r < 4; r++) acc[a][c][r] = 0.f;

    for (int k0 = 0; k0 < K; k0 += 32) {
        __syncthreads();
#pragma unroll
        for (int i = 0; i < 2; i++) {
            int c = tid + i * 256;         // 512 chunks of 16B per tile
            int row = c >> 2, kc = c & 3;  // 4 chunks per 32-elem row
            *(uint4*)(sA + row * LS + kc * 8) =
                *(const uint4*)(A + (size_t)(m0 + row) * K + k0 + kc * 8);
            *(uint4*)(sB + row * LS + kc * 8) =
                *(const uint4*)(Bt + (size_t)(n0 + row) * K + k0 + kc * 8);
        }
        __syncthreads();
        bf16x8 af[4], bfr[4];
#pragma unroll
        for (int t = 0; t < 4; t++) {
            af[t] = *(const bf16x8*)(sA + (wm + t * 16 + l15) * LS + quad * 8);
            bfr[t] = *(const bf16x8*)(sB + (wn + t * 16 + l15) * LS + quad * 8);
        }
#pragma unroll
        for (int mi = 0; mi < 4; mi++)
#pragma unroll
            for (int ni = 0; ni < 4; ni++)
                acc[mi][ni] = __builtin_amdgcn_mfma_f32_16x16x32_bf16(
                    af[mi], bfr[ni], acc[mi][ni], 0, 0, 0);
    }
#pragma unroll
    for (int mi = 0; mi < 4; mi++)
#pragma unroll
        for (int ni = 0; ni < 4; ni++)
#pragma unroll
            for (int r = 0; r < 4; r++) {
                int row = m0 + wm + mi * 16 + quad * 4 + r;
                int col = n0 + wn + ni * 16 + l15;
                if (F32OUT)
                    Cf[(size_t)row * N + col] = acc[mi][ni][r];
                else
                    Cb[(size_t)row * N + col] = (bf16)acc[mi][ni][r];
            }
}

// ---------------------------------------------------------------------------
// V [4096][2048] (row = b*2048+s, col = head*128+h) -> Vt[b][head][h][s]
__global__ void k_vtrans(const unsigned short* __restrict__ V,
                         unsigned short* __restrict__ Vt) {
    __shared__ __align__(16) unsigned short tile[64 * 72];
    const int tid = threadIdx.x;
    const int m0 = blockIdx.x * 64;  // s-dim (with b folded)
    const int n0 = blockIdx.y * 64;  // nh-dim
    const int r8 = tid >> 3, c8 = (tid & 7) * 8;
#pragma unroll
    for (int i = 0; i < 2; i++) {
        int row = r8 + i * 32;
        *(uint4*)(tile + row * 72 + c8) =
            *(const uint4*)(V + (size_t)(m0 + row) * 2048 + n0 + c8);
    }
    __syncthreads();
    const int b = m0 >> 11, s0 = m0 & 2047;
#pragma unroll
    for (int i = 0; i < 2; i++) {
        int nl = r8 + i * 32;
        int nh = n0 + nl;
        u16x8 o;
#pragma unroll
        for (int j = 0; j < 8; j++) o[j] = tile[(c8 + j) * 72 + nl];
        *(u16x8*)(Vt + (size_t)(b * 2048 + nh) * 2048 + s0 + c8) = o;
    }
}

// ---------------------------------------------------------------------------
// Flash-style causal prefill attention.
// Q (pre-scaled by 1/sqrt(128)), Kc: [4096][2048]; Vt: [b][head][h][s]; O: [4096][2048]
// grid (32 qtiles, 16 heads, 2 b), 256 threads = 4 waves x 16 q-rows.
__global__ __launch_bounds__(256) void k_attn(
    const bf16* __restrict__ Q, const bf16* __restrict__ Kc,
    const bf16* __restrict__ Vt, bf16* __restrict__ O) {
    constexpr int RK = 136, RV = 72, RP = 72;  // padded strides, multiples of 8
    __shared__ __align__(16) bf16 sK[64 * RK];
    __shared__ __align__(16) bf16 sV[128 * RV];
    __shared__ __align__(16) bf16 sP[4][16 * RP];
    const int tid = threadIdx.x;
    const int wave = tid >> 6, lane = tid & 63;
    const int quad = lane >> 4, l15 = lane & 15;
    const int qt = blockIdx.x, head = blockIdx.y, b = blockIdx.z;
    const int qb = qt * 64;

    // Preload Q fragments (A-layout): row = qb + wave*16 + l15
    const bf16* Qrow = Q + (size_t)(b * 2048 + qb + wave * 16 + l15) * 2048 + head * 128;
    bf16x8 qf[4];
#pragma unroll
    for (int kc = 0; kc < 4; kc++) qf[kc] = *(const bf16x8*)(Qrow + kc * 32 + quad * 8);

    f32x4 accO[8];
#pragma unroll
    for (int hn = 0; hn < 8; hn++)
#pragma unroll
        for (int r = 0; r < 4; r++) accO[hn][r] = 0.f;
    float m_i[4], l_i[4];
#pragma unroll
    for (int r = 0; r < 4; r++) { m_i[r] = -INFINITY; l_i[r] = 0.f; }

    const bf16* Kbase = Kc + (size_t)(b * 2048) * 2048 + head * 128;
    const bf16* Vbase = Vt + (size_t)(b * 2048 + head * 128) * 2048;
    const int qrow_base = qb + wave * 16 + quad * 4;

    for (int t0 = 0; t0 <= qb; t0 += 64) {
        __syncthreads();
#pragma unroll
        for (int i = 0; i < 4; i++) {
            int c = tid + i * 256;  // 1024 chunks of 16B each for K and V
            {
                int key = c >> 4, hc = c & 15;
                *(uint4*)(sK + key * RK + hc * 8) =
                    *(const uint4*)(Kbase + (size_t)(t0 + key) * 2048 + hc * 8);
            }
            {
                int h = c >> 3, kg = c & 7;
                *(uint4*)(sV + h * RV + kg * 8) =
                    *(const uint4*)(Vbase + (size_t)h * 2048 + t0 + kg * 8);
            }
        }
        __syncthreads();

        // S = Q K^T  (16 q-rows x 64 keys per wave)
        f32x4 sc[4];
#pragma unroll
        for (int nt = 0; nt < 4; nt++) {
#pragma unroll
            for (int r = 0; r < 4; r++) sc[nt][r] = 0.f;
#pragma unroll
            for (int kc = 0; kc < 4; kc++) {
                bf16x8 kf = *(const bf16x8*)(sK + (nt * 16 + l15) * RK + kc * 32 + quad * 8);
                sc[nt] = __builtin_amdgcn_mfma_f32_16x16x32_bf16(qf[kc], kf, sc[nt], 0, 0, 0);
            }
        }

        // online softmax (per C-layout row r)
#pragma unroll
        for (int r = 0; r < 4; r++) {
            const int qg = qrow_base + r;
            float mt = -INFINITY;
#pragma unroll
            for (int nt = 0; nt < 4; nt++) {
                int key = t0 + nt * 16 + l15;
                float v = sc[nt][r];
                if (key > qg) v = -INFINITY;
                sc[nt][r] = v;
                mt = fmaxf(mt, v);
            }
#pragma unroll
            for (int off = 1; off <= 8; off <<= 1) mt = fmaxf(mt, __shfl_xor(mt, off));
            float mn = fmaxf(m_i[r], mt);
            float alpha = __expf(m_i[r] - mn);
            float rs = 0.f;
#pragma unroll
            for (int nt = 0; nt < 4; nt++) {
                float p = __expf(sc[nt][r] - mn);
                sc[nt][r] = p;
                rs += p;
            }
#pragma unroll
            for (int off = 1; off <= 8; off <<= 1) rs += __shfl_xor(rs, off);
            l_i[r] = l_i[r] * alpha + rs;
            m_i[r] = mn;
#pragma unroll
            for (int hn = 0; hn < 8; hn++) accO[hn][r] *= alpha;
        }

        // P: C-layout -> LDS -> A-layout (per-wave buffer, in-order LDS within wave)
        bf16* sPw = sP[wave];
#pragma unroll
        for (int nt = 0; nt < 4; nt++)
#pragma unroll
            for (int r = 0; r < 4; r++)
                sPw[(quad * 4 + r) * RP + nt * 16 + l15] = (bf16)sc[nt][r];

        // O += P V
#pragma unroll
        for (int kc = 0; kc < 2; kc++) {
            bf16x8 pf = *(const bf16x8*)(sPw + l15 * RP + kc * 32 + quad * 8);
#pragma unroll
            for (int hn = 0; hn < 8; hn++) {
                bf16x8 vf = *(const bf16x8*)(sV + (hn * 16 + l15) * RV + kc * 32 + quad * 8);
                accO[hn] = __builtin_amdgcn_mfma_f32_16x16x32_bf16(pf, vf, accO[hn], 0, 0, 0);
            }
        }
    }

    float inv[4];
#pragma unroll
    for (int r = 0; r < 4; r++) inv[r] = 1.f / l_i[r];
    bf16* Orow = O + (size_t)(b * 2048 + qb + wave * 16) * 2048 + head * 128;
#pragma unroll
    for (int hn = 0; hn < 8; hn++)
#pragma unroll
        for (int r = 0; r < 4; r++)
            Orow[(size_t)(quad * 4 + r) * 2048 + hn * 16 + l15] =
                (bf16)(accO[hn][r] * inv[r]);
}

// ---------------------------------------------------------------------------
// GEMV: y[b][n] = sum_k x[b][k] * Wt[n][k].  grid (N/256, B), 256 threads.
__global__ void k_gemv(const bf16* __restrict__ x, const bf16* __restrict__ Wt,
                       bf16* __restrict__ yb, float* __restrict__ yf, int N) {
    __shared__ __align__(16) bf16 sx[2048];
    const int tid = threadIdx.x;
    const int b = blockIdx.y;
    *(uint4*)(sx + tid * 8) = *(const uint4*)(x + (size_t)b * 2048 + tid * 8);
    __syncthreads();
    const int n = blockIdx.x * 256 + tid;
    const bf16* w = Wt + (size_t)n * 2048;
    float s = 0.f;
    for (int k = 0; k < 2048; k += 8) {
        bf16v8 xv = *(const bf16v8*)(sx + k);
        bf16v8 wv = *(const bf16v8*)(w + k);
#pragma unroll
        for (int j = 0; j < 8; j++) s += (float)xv[j] * (float)wv[j];
    }
    if (yb) yb[(size_t)b * N + n] = (bf16)s;
    if (yf) yf[(size_t)b * N + n] = s;
}

// ---------------------------------------------------------------------------
// Decode attention: per (head, b) block. q1 pre-scaled. 2049 keys (cache + new).
__global__ __launch_bounds__(256) void k_decode_attn(
    const bf16* __restrict__ Kc, const bf16* __restrict__ Vt,
    const bf16* __restrict__ q1, const bf16* __restrict__ k1,
    const bf16* __restrict__ v1, bf16* __restrict__ o1) {
    __shared__ float scb[2049];
    __shared__ __align__(16) bf16 sq[128];
    __shared__ float redm[4];
    __shared__ float reds[4];
    __shared__ float ph[256];
    const int tid = threadIdx.x;
    const int head = blockIdx.x, b = blockIdx.y;
    const int lane = tid & 63, wave = tid >> 6;

    if (tid < 16)
        *(uint4*)(sq + tid * 8) = *(const uint4*)(q1 + (size_t)b * 2048 + head * 128 + tid * 8);
    __syncthreads();

#pragma unroll
    for (int i = 0; i < 8; i++) {
        int t = tid + i * 256;
        const bf16* kr = Kc + (size_t)(b * 2048 + t) * 2048 + head * 128;
        float s = 0.f;
        for (int k = 0; k < 128; k += 8) {
            bf16v8 kv = *(const bf16v8*)(kr + k);
            bf16v8 qv = *(const bf16v8*)(sq + k);
#pragma unroll
            for (int j = 0; j < 8; j++) s += (float)qv[j] * (float)kv[j];
        }
        scb[t] = s;
    }
    if (tid == 0) {
        const bf16* kr = k1 + (size_t)b * 2048 + head * 128;
        float s = 0.f;
        for (int k = 0; k < 128; k++) s += (float)sq[k] * (float)kr[k];
        scb[2048] = s;
    }
    __syncthreads();

    float m = -INFINITY;
#pragma unroll
    for (int i = 0; i < 8; i++) m = fmaxf(m, scb[tid + i * 256]);
    if (tid == 0) m = fmaxf(m, scb[2048]);
#pragma unroll
    for (int off = 1; off <= 32; off <<= 1) m = fmaxf(m, __shfl_xor(m, off));
    if (lane == 0) redm[wave] = m;
    __syncthreads();
    const float gm = fmaxf(fmaxf(redm[0], redm[1]), fmaxf(redm[2], redm[3]));

    float ls = 0.f;
#pragma unroll
    for (int i = 0; i < 8; i++) {
        int t = tid + i * 256;
        float p = __expf(scb[t] - gm);
        scb[t] = p;
        ls += p;
    }
    if (tid == 0) {
        float p = __expf(scb[2048] - gm);
        scb[2048] = p;
        ls += p;
    }
#pragma unroll
    for (int off = 1; off <= 32; off <<= 1) ls += __shfl_xor(ls, off);
    if (lane == 0) reds[wave] = ls;
    __syncthreads();
    const float gs = reds[0] + reds[1] + reds[2] + reds[3];

    const int h = tid & 127, part = tid >> 7;
    const bf16* vr = Vt + (size_t)(b * 2048 + head * 128 + h) * 2048 + part * 1024;
    float acc = 0.f;
    for (int t = 0; t < 1024; t += 8) {
        bf16v8 vv = *(const bf16v8*)(vr + t);
#pragma unroll
        for (int j = 0; j < 8; j++) acc += scb[part * 1024 + t + j] * (float)vv[j];
    }
    ph[tid] = acc;
    __syncthreads();
    if (part == 0) {
        float tot = ph[tid] + ph[tid + 128] +
                    scb[2048] * (float)v1[(size_t)b * 2048 + head * 128 + h];
        o1[(size_t)b * 2048 + head * 128 + h] = (bf16)(tot / gs);
    }
}

// ---------------------------------------------------------------------------
extern "C" void kernel_launch(void* const* d_in, const int* in_sizes, int n_in,
                              void* d_out, int out_size, void* d_ws, size_t ws_size,
                              hipStream_t stream) {
    const float* x  = (const float*)d_in[0];   // [2,2048,2048]
    const float* xn = (const float*)d_in[1];   // [2,1,2048]
    const float* wq = (const float*)d_in[2];   // [2048,16,128]
    const float* wk = (const float*)d_in[3];
    const float* wv = (const float*)d_in[4];
    const float* wo = (const float*)d_in[5];
    float* out = (float*)d_out;

    char* p = (char*)d_ws;
    auto alloc = [&](size_t bytes) {
        char* r = p;
        p += (bytes + 255) & ~(size_t)255;
        return r;
    };
    bf16* xb  = (bf16*)alloc((size_t)4096 * 2048 * 2);
    bf16* xnb = (bf16*)alloc((size_t)2 * 2048 * 2);
    bf16* wqT = (bf16*)alloc((size_t)2048 * 2048 * 2);
    bf16* wkT = (bf16*)alloc((size_t)2048 * 2048 * 2);
    bf16* wvT = (bf16*)alloc((size_t)2048 * 2048 * 2);
    bf16* wob = (bf16*)alloc((size_t)2048 * 2048 * 2);
    bf16* Qb  = (bf16*)alloc((size_t)4096 * 2048 * 2);
    bf16* Kb  = (bf16*)alloc((size_t)4096 * 2048 * 2);
    bf16* Vb  = (bf16*)alloc((size_t)4096 * 2048 * 2);
    bf16* Vtb = (bf16*)alloc((size_t)4096 * 2048 * 2);
    bf16* AOb = (bf16*)alloc((size_t)4096 * 2048 * 2);
    bf16* q1b = (bf16*)alloc((size_t)2 * 2048 * 2);
    bf16* k1b = (bf16*)alloc((size_t)2 * 2048 * 2);
    bf16* v1b = (bf16*)alloc((size_t)2 * 2048 * 2);
    bf16* o1b = (bf16*)alloc((size_t)2 * 2048 * 2);

    const float scale = 0.08838834764831845f;  // 1/sqrt(128), folded into wq

    k_cvt<<<8192, 256, 0, stream>>>(x, xb, 8388608, 1.f);
    k_cvt<<<4, 256, 0, stream>>>(xn, xnb, 4096, 1.f);
    k_wt<<<dim3(64, 64), 256, 0, stream>>>(wq, wqT, scale);
    k_wt<<<dim3(64, 64), 256, 0, stream>>>(wk, wkT, 1.f);
    k_wt<<<dim3(64, 64), 256, 0, stream>>>(wv, wvT, 1.f);
    k_cvt<<<4096, 256, 0, stream>>>(wo, wob, 4194304, 1.f);

    dim3 gg(32, 16);
    k_gemm_bt<0><<<gg, 256, 0, stream>>>(xb, wqT, Qb, nullptr, 4096, 2048, 2048);
    k_gemm_bt<0><<<gg, 256, 0, stream>>>(xb, wkT, Kb, nullptr, 4096, 2048, 2048);
    k_gemm_bt<0><<<gg, 256, 0, stream>>>(xb, wvT, Vb, nullptr, 4096, 2048, 2048);
    k_vtrans<<<dim3(64, 32), 256, 0, stream>>>((const unsigned short*)Vb,
                                               (unsigned short*)Vtb);
    k_attn<<<dim3(32, 16, 2), 256, 0, stream>>>(Qb, Kb, Vtb, AOb);
    k_gemm_bt<1><<<gg, 256, 0, stream>>>(AOb, wob, nullptr, out, 4096, 2048, 2048);

    // decode
    k_gemv<<<dim3(8, 2), 256, 0, stream>>>(xnb, wqT, q1b, nullptr, 2048);
    k_gemv<<<dim3(8, 2), 256, 0, stream>>>(xnb, wkT, k1b, nullptr, 2048);
    k_gemv<<<dim3(8, 2), 256, 0, stream>>>(xnb, wvT, v1b, nullptr, 2048);
    k_decode_attn<<<dim3(16, 2), 256, 0, stream>>>(Kb, Vtb, q1b, k1b, v1b, o1b);
    k_gemv<<<dim3(8, 2), 256, 0, stream>>>(o1b, wob, nullptr, out + 8388608, 2048);
}

// Round 2
// 737.024 us; speedup vs baseline: 1.0544x; 1.0544x over previous
//
#include <hip/hip_runtime.h>
#include <cmath>

typedef __bf16 bf16;
typedef short bf16x8 __attribute__((ext_vector_type(8)));   // MFMA A/B fragment (bf16 bit patterns)
typedef __bf16 bf16v8 __attribute__((ext_vector_type(8)));  // arithmetic bf16 vector
typedef __bf16 bf16v4 __attribute__((ext_vector_type(4)));
typedef float f32x4 __attribute__((ext_vector_type(4)));
typedef unsigned short u16x8 __attribute__((ext_vector_type(8)));

// async global->LDS, 16B per lane. LDS base must be wave-uniform; HW adds lane*16.
__device__ __forceinline__ void load_lds16(const void* g, void* l) {
    __builtin_amdgcn_global_load_lds(
        (const __attribute__((address_space(1))) void*)g,
        (__attribute__((address_space(3))) void*)l, 16, 0, 0);
}

// ---------------------------------------------------------------------------
// fp32 -> bf16 elementwise convert (optionally scaled). n multiple of 4.
__global__ void k_cvt(const float* __restrict__ in, bf16* __restrict__ out,
                      int n, float scale) {
    int i = (blockIdx.x * 256 + threadIdx.x) * 4;
    if (i >= n) return;
    float4 v = *(const float4*)(in + i);
    bf16v4 o;
    o[0] = (bf16)(v.x * scale);
    o[1] = (bf16)(v.y * scale);
    o[2] = (bf16)(v.z * scale);
    o[3] = (bf16)(v.w * scale);
    *(bf16v4*)(out + i) = o;
}

// ---------------------------------------------------------------------------
// Weight convert + transpose: w[K=2048][N=2048] f32 -> wt[N][K] bf16 (scaled).
__global__ void k_wt(const float* __restrict__ w, bf16* __restrict__ wt, float scale) {
    __shared__ float tile[32][33];
    const int tid = threadIdx.x;
    const int tx = tid & 31, ty = tid >> 5;  // 32 x 8
    const int k0 = blockIdx.x * 32, n0 = blockIdx.y * 32;
#pragma unroll
    for (int i = 0; i < 4; i++) {
        int kk = ty + i * 8;
        tile[kk][tx] = w[(size_t)(k0 + kk) * 2048 + n0 + tx];
    }
    __syncthreads();
#pragma unroll
    for (int i = 0; i < 4; i++) {
        int nn = ty + i * 8;
        wt[(size_t)(n0 + nn) * 2048 + k0 + tx] = (bf16)(tile[tx][nn] * scale);
    }
}

// ---------------------------------------------------------------------------
// bf16 GEMM: C[M][N] = A[M][K] * Bt[N][K]^T.  128x128 tile, 4 waves (2x2),
// each wave 64x64 via 4x4 grid of 16x16x32 MFMA tiles. BK=32.
// m97-style: global_load_lds width-16 staging, unpadded LDS.
template <int F32OUT>
__global__ __launch_bounds__(256) void k_gemm_bt(
    const bf16* __restrict__ A, const bf16* __restrict__ Bt,
    bf16* __restrict__ Cb, float* __restrict__ Cf, int M, int N, int K) {
    __shared__ __align__(16) bf16 sA[128 * 32];
    __shared__ __align__(16) bf16 sB[128 * 32];
    const int tid = threadIdx.x;
    const int wave = tid >> 6, lane = tid & 63;
    const int quad = lane >> 4, l15 = lane & 15;
    const int wm = (wave >> 1) * 64, wn = (wave & 1) * 64;
    const int m0 = blockIdx.x * 128, n0 = blockIdx.y * 128;

    f32x4 acc[4][4];
#pragma unroll
    for (int a = 0; a < 4; a++)
#pragma unroll
        for (int c = 0; c < 4; c++)
#pragma unroll
            for (int r = 0; r < 4; r++) acc[a][c][r] = 0.f;

    for (int k0 = 0; k0 < K; k0 += 32) {
        __syncthreads();
#pragma unroll
        for (int i = 0; i < 2; i++) {
            const int slotBase = wave * 128 + i * 64;  // wave-uniform
            const int slot = slotBase + lane;
            const int row = slot >> 2, kc = slot & 3;  // 4x16B chunks per 32-elem row
            load_lds16(A + (size_t)(m0 + row) * K + k0 + kc * 8, &sA[slotBase * 8]);
            load_lds16(Bt + (size_t)(n0 + row) * K + k0 + kc * 8, &sB[slotBase * 8]);
        }
        __syncthreads();
        bf16x8 af[4], bfr[4];
#pragma unroll
        for (int t = 0; t < 4; t++) {
            af[t] = *(const bf16x8*)(sA + (wm + t * 16 + l15) * 32 + quad * 8);
            bfr[t] = *(const bf16x8*)(sB + (wn + t * 16 + l15) * 32 + quad * 8);
        }
#pragma unroll
        for (int mi = 0; mi < 4; mi++)
#pragma unroll
            for (int ni = 0; ni < 4; ni++)
                acc[mi][ni] = __builtin_amdgcn_mfma_f32_16x16x32_bf16(
                    af[mi], bfr[ni], acc[mi][ni], 0, 0, 0);
    }
#pragma unroll
    for (int mi = 0; mi < 4; mi++)
#pragma unroll
        for (int ni = 0; ni < 4; ni++)
#pragma unroll
            for (int r = 0; r < 4; r++) {
                int row = m0 + wm + mi * 16 + quad * 4 + r;
                int col = n0 + wn + ni * 16 + l15;
                if (F32OUT)
                    Cf[(size_t)row * N + col] = acc[mi][ni][r];
                else
                    Cb[(size_t)row * N + col] = (bf16)acc[mi][ni][r];
            }
}

// ---------------------------------------------------------------------------
// V [4096][2048] (row = b*2048+s, col = head*128+h) -> Vt[b][head][h][s]
__global__ void k_vtrans(const unsigned short* __restrict__ V,
                         unsigned short* __restrict__ Vt) {
    __shared__ __align__(16) unsigned short tile[64 * 72];
    const int tid = threadIdx.x;
    const int m0 = blockIdx.x * 64;  // s-dim (with b folded)
    const int n0 = blockIdx.y * 64;  // nh-dim
    const int r8 = tid >> 3, c8 = (tid & 7) * 8;
#pragma unroll
    for (int i = 0; i < 2; i++) {
        int row = r8 + i * 32;
        *(uint4*)(tile + row * 72 + c8) =
            *(const uint4*)(V + (size_t)(m0 + row) * 2048 + n0 + c8);
    }
    __syncthreads();
    const int b = m0 >> 11, s0 = m0 & 2047;
#pragma unroll
    for (int i = 0; i < 2; i++) {
        int nl = r8 + i * 32;
        int nh = n0 + nl;
        u16x8 o;
#pragma unroll
        for (int j = 0; j < 8; j++) o[j] = tile[(c8 + j) * 72 + nl];
        *(u16x8*)(Vt + (size_t)(b * 2048 + nh) * 2048 + s0 + c8) = o;
    }
}

// ---------------------------------------------------------------------------
// Flash-style causal prefill attention, v2.
// - Q pre-scaled by (1/sqrt(128))*log2(e); softmax in exp2 domain.
// - Block pairs q-tiles qt and 31-qt -> every block does exactly 17
//   128-key iterations (perfect balance; 512 blocks = 2/CU, all resident).
// - K/V staged via global_load_lds w16 into XOR-swizzled unpadded LDS
//   (chunk' = chunk ^ (row&7)) -> conflict-free b128 frag reads.
// - LDS = 32K (sK) + 32K (sV) + 16K (sP) = 80 KB exactly -> 2 blocks/CU.
__global__ __launch_bounds__(256) void k_attn(
    const bf16* __restrict__ Q, const bf16* __restrict__ Kc,
    const bf16* __restrict__ Vt, bf16* __restrict__ O) {
    __shared__ __align__(16) bf16 sK[128 * 128];
    __shared__ __align__(16) bf16 sV[128 * 128];
    __shared__ __align__(16) bf16 sP[4][16 * 128];
    const int tid = threadIdx.x;
    const int wave = tid >> 6, lane = tid & 63;
    const int quad = lane >> 4, l15 = lane & 15;
    const int head = blockIdx.y, b = blockIdx.z;
    const bf16* Kbase = Kc + (size_t)(b * 2048) * 2048 + head * 128;
    const bf16* Vbase = Vt + (size_t)(b * 2048 + head * 128) * 2048;
    bf16* sPw = sP[wave];
    const int swz = l15 & 7;  // row&7 for frag reads (row = *16 + l15)

    for (int phase = 0; phase < 2; ++phase) {
        const int qt = phase ? (31 - blockIdx.x) : blockIdx.x;
        const int qb = qt * 64;
        const int nkt = (qt >> 1) + 1;

        const bf16* Qrow = Q + (size_t)(b * 2048 + qb + wave * 16 + l15) * 2048 + head * 128;
        bf16x8 qf[4];
#pragma unroll
        for (int kc = 0; kc < 4; kc++) qf[kc] = *(const bf16x8*)(Qrow + kc * 32 + quad * 8);

        f32x4 accO[8];
#pragma unroll
        for (int hn = 0; hn < 8; hn++)
#pragma unroll
            for (int r = 0; r < 4; r++) accO[hn][r] = 0.f;
        float m_i[4], l_i[4];
#pragma unroll
        for (int r = 0; r < 4; r++) { m_i[r] = -INFINITY; l_i[r] = 0.f; }
        const int qg_base = qb + wave * 16 + quad * 4;

        for (int kt = 0; kt < nkt; ++kt) {
            const int t0 = kt * 128;
            __syncthreads();
            // stage K (128 keys x 128 h) and V (128 h x 128 s), XOR-swizzled
#pragma unroll
            for (int i = 0; i < 8; ++i) {
                const int slotBase = wave * 512 + i * 64;  // wave-uniform
                const int slot = slotBase + lane;
                const int rw = slot >> 4, cp = slot & 15;
                const int c = cp ^ (rw & 7);
                load_lds16(Kbase + (size_t)(t0 + rw) * 2048 + c * 8, &sK[slotBase * 8]);
                load_lds16(Vbase + (size_t)rw * 2048 + t0 + c * 8, &sV[slotBase * 8]);
            }
            __syncthreads();

            // S = Q K^T : 16 q-rows x 128 keys per wave
            f32x4 sc[8];
#pragma unroll
            for (int nt = 0; nt < 8; nt++) {
#pragma unroll
                for (int r = 0; r < 4; r++) sc[nt][r] = 0.f;
#pragma unroll
                for (int kc = 0; kc < 4; kc++) {
                    bf16x8 kf = *(const bf16x8*)(
                        sK + (nt * 16 + l15) * 128 + ((kc * 4 + quad) ^ swz) * 8);
                    sc[nt] = __builtin_amdgcn_mfma_f32_16x16x32_bf16(qf[kc], kf, sc[nt], 0, 0, 0);
                }
            }

            // online softmax (exp2 domain), l kept as per-lane partials
#pragma unroll
            for (int r = 0; r < 4; r++) {
                const int qg = qg_base + r;
                float mt = -INFINITY;
#pragma unroll
                for (int nt = 0; nt < 8; nt++) {
                    int key = t0 + nt * 16 + l15;
                    float v = sc[nt][r];
                    if (key > qg) v = -INFINITY;
                    sc[nt][r] = v;
                    mt = fmaxf(mt, v);
                }
#pragma unroll
                for (int off = 1; off <= 8; off <<= 1) mt = fmaxf(mt, __shfl_xor(mt, off));
                float mn = fmaxf(m_i[r], mt);
                float alpha = __builtin_amdgcn_exp2f(m_i[r] - mn);
                m_i[r] = mn;
                float rs = 0.f;
#pragma unroll
                for (int nt = 0; nt < 8; nt++) {
                    float p = __builtin_amdgcn_exp2f(sc[nt][r] - mn);
                    sc[nt][r] = p;
                    rs += p;
                }
                l_i[r] = l_i[r] * alpha + rs;  // per-lane partial; reduced at end
#pragma unroll
                for (int hn = 0; hn < 8; hn++) accO[hn][r] *= alpha;
            }

            // P: C-layout -> per-wave LDS (same XOR swizzle) -> A-layout
#pragma unroll
            for (int nt = 0; nt < 8; nt++)
#pragma unroll
                for (int r = 0; r < 4; r++) {
                    const int prow = quad * 4 + r;
                    sPw[prow * 128 + ((2 * nt + (l15 >> 3)) ^ (prow & 7)) * 8 + (l15 & 7)] =
                        (bf16)sc[nt][r];
                }

            // O += P V
#pragma unroll
            for (int kc = 0; kc < 4; kc++) {
                bf16x8 pf = *(const bf16x8*)(
                    sPw + l15 * 128 + ((kc * 4 + quad) ^ swz) * 8);
#pragma unroll
                for (int hn = 0; hn < 8; hn++) {
                    bf16x8 vf = *(const bf16x8*)(
                        sV + (hn * 16 + l15) * 128 + ((kc * 4 + quad) ^ swz) * 8);
                    accO[hn] = __builtin_amdgcn_mfma_f32_16x16x32_bf16(pf, vf, accO[hn], 0, 0, 0);
                }
            }
        }

        // reduce l partials across the 16-lane row group, then write O
        float inv[4];
#pragma unroll
        for (int r = 0; r < 4; r++) {
            float l = l_i[r];
#pragma unroll
            for (int off = 1; off <= 8; off <<= 1) l += __shfl_xor(l, off);
            inv[r] = 1.f / l;
        }
        bf16* Orow = O + (size_t)(b * 2048 + qb + wave * 16) * 2048 + head * 128;
#pragma unroll
        for (int hn = 0; hn < 8; hn++)
#pragma unroll
            for (int r = 0; r < 4; r++)
                Orow[(size_t)(quad * 4 + r) * 2048 + hn * 16 + l15] =
                    (bf16)(accO[hn][r] * inv[r]);
    }
}

// ---------------------------------------------------------------------------
// GEMV: y[b][n] = sum_k x[b][k] * Wt[n][k].  grid (N/256, B), 256 threads.
__global__ void k_gemv(const bf16* __restrict__ x, const bf16* __restrict__ Wt,
                       bf16* __restrict__ yb, float* __restrict__ yf, int N) {
    __shared__ __align__(16) bf16 sx[2048];
    const int tid = threadIdx.x;
    const int b = blockIdx.y;
    *(uint4*)(sx + tid * 8) = *(const uint4*)(x + (size_t)b * 2048 + tid * 8);
    __syncthreads();
    const int n = blockIdx.x * 256 + tid;
    const bf16* w = Wt + (size_t)n * 2048;
    float s = 0.f;
    for (int k = 0; k < 2048; k += 8) {
        bf16v8 xv = *(const bf16v8*)(sx + k);
        bf16v8 wv = *(const bf16v8*)(w + k);
#pragma unroll
        for (int j = 0; j < 8; j++) s += (float)xv[j] * (float)wv[j];
    }
    if (yb) yb[(size_t)b * N + n] = (bf16)s;
    if (yf) yf[(size_t)b * N + n] = s;
}

// ---------------------------------------------------------------------------
// Decode attention: per (head, b) block. q1 pre-scaled (log2e folded -> exp2).
__global__ __launch_bounds__(256) void k_decode_attn(
    const bf16* __restrict__ Kc, const bf16* __restrict__ Vt,
    const bf16* __restrict__ q1, const bf16* __restrict__ k1,
    const bf16* __restrict__ v1, bf16* __restrict__ o1) {
    __shared__ float scb[2049];
    __shared__ __align__(16) bf16 sq[128];
    __shared__ float redm[4];
    __shared__ float reds[4];
    __shared__ float ph[256];
    const int tid = threadIdx.x;
    const int head = blockIdx.x, b = blockIdx.y;
    const int lane = tid & 63, wave = tid >> 6;

    if (tid < 16)
        *(uint4*)(sq + tid * 8) = *(const uint4*)(q1 + (size_t)b * 2048 + head * 128 + tid * 8);
    __syncthreads();

#pragma unroll
    for (int i = 0; i < 8; i++) {
        int t = tid + i * 256;
        const bf16* kr = Kc + (size_t)(b * 2048 + t) * 2048 + head * 128;
        float s = 0.f;
        for (int k = 0; k < 128; k += 8) {
            bf16v8 kv = *(const bf16v8*)(kr + k);
            bf16v8 qv = *(const bf16v8*)(sq + k);
#pragma unroll
            for (int j = 0; j < 8; j++) s += (float)qv[j] * (float)kv[j];
        }
        scb[t] = s;
    }
    if (tid == 0) {
        const bf16* kr = k1 + (size_t)b * 2048 + head * 128;
        float s = 0.f;
        for (int k = 0; k < 128; k++) s += (float)sq[k] * (float)kr[k];
        scb[2048] = s;
    }
    __syncthreads();

    float m = -INFINITY;
#pragma unroll
    for (int i = 0; i < 8; i++) m = fmaxf(m, scb[tid + i * 256]);
    if (tid == 0) m = fmaxf(m, scb[2048]);
#pragma unroll
    for (int off = 1; off <= 32; off <<= 1) m = fmaxf(m, __shfl_xor(m, off));
    if (lane == 0) redm[wave] = m;
    __syncthreads();
    const float gm = fmaxf(fmaxf(redm[0], redm[1]), fmaxf(redm[2], redm[3]));

    float ls = 0.f;
#pragma unroll
    for (int i = 0; i < 8; i++) {
        int t = tid + i * 256;
        float p = __builtin_amdgcn_exp2f(scb[t] - gm);
        scb[t] = p;
        ls += p;
    }
    if (tid == 0) {
        float p = __builtin_amdgcn_exp2f(scb[2048] - gm);
        scb[2048] = p;
        ls += p;
    }
#pragma unroll
    for (int off = 1; off <= 32; off <<= 1) ls += __shfl_xor(ls, off);
    if (lane == 0) reds[wave] = ls;
    __syncthreads();
    const float gs = reds[0] + reds[1] + reds[2] + reds[3];

    const int h = tid & 127, part = tid >> 7;
    const bf16* vr = Vt + (size_t)(b * 2048 + head * 128 + h) * 2048 + part * 1024;
    float acc = 0.f;
    for (int t = 0; t < 1024; t += 8) {
        bf16v8 vv = *(const bf16v8*)(vr + t);
#pragma unroll
        for (int j = 0; j < 8; j++) acc += scb[part * 1024 + t + j] * (float)vv[j];
    }
    ph[tid] = acc;
    __syncthreads();
    if (part == 0) {
        float tot = ph[tid] + ph[tid + 128] +
                    scb[2048] * (float)v1[(size_t)b * 2048 + head * 128 + h];
        o1[(size_t)b * 2048 + head * 128 + h] = (bf16)(tot / gs);
    }
}

// ---------------------------------------------------------------------------
extern "C" void kernel_launch(void* const* d_in, const int* in_sizes, int n_in,
                              void* d_out, int out_size, void* d_ws, size_t ws_size,
                              hipStream_t stream) {
    const float* x  = (const float*)d_in[0];   // [2,2048,2048]
    const float* xn = (const float*)d_in[1];   // [2,1,2048]
    const float* wq = (const float*)d_in[2];   // [2048,16,128]
    const float* wk = (const float*)d_in[3];
    const float* wv = (const float*)d_in[4];
    const float* wo = (const float*)d_in[5];
    float* out = (float*)d_out;

    char* p = (char*)d_ws;
    auto alloc = [&](size_t bytes) {
        char* r = p;
        p += (bytes + 255) & ~(size_t)255;
        return r;
    };
    bf16* xb  = (bf16*)alloc((size_t)4096 * 2048 * 2);
    bf16* xnb = (bf16*)alloc((size_t)2 * 2048 * 2);
    bf16* wqT = (bf16*)alloc((size_t)2048 * 2048 * 2);
    bf16* wkT = (bf16*)alloc((size_t)2048 * 2048 * 2);
    bf16* wvT = (bf16*)alloc((size_t)2048 * 2048 * 2);
    bf16* wob = (bf16*)alloc((size_t)2048 * 2048 * 2);
    bf16* Qb  = (bf16*)alloc((size_t)4096 * 2048 * 2);
    bf16* Kb  = (bf16*)alloc((size_t)4096 * 2048 * 2);
    bf16* Vb  = (bf16*)alloc((size_t)4096 * 2048 * 2);
    bf16* Vtb = (bf16*)alloc((size_t)4096 * 2048 * 2);
    bf16* AOb = (bf16*)alloc((size_t)4096 * 2048 * 2);
    bf16* q1b = (bf16*)alloc((size_t)2 * 2048 * 2);
    bf16* k1b = (bf16*)alloc((size_t)2 * 2048 * 2);
    bf16* v1b = (bf16*)alloc((size_t)2 * 2048 * 2);
    bf16* o1b = (bf16*)alloc((size_t)2 * 2048 * 2);

    // 1/sqrt(128) * log2(e): softmax runs in exp2 domain
    const float qscale = 0.08838834764831845f * 1.4426950408889634f;

    k_cvt<<<8192, 256, 0, stream>>>(x, xb, 8388608, 1.f);
    k_cvt<<<4, 256, 0, stream>>>(xn, xnb, 4096, 1.f);
    k_wt<<<dim3(64, 64), 256, 0, stream>>>(wq, wqT, qscale);
    k_wt<<<dim3(64, 64), 256, 0, stream>>>(wk, wkT, 1.f);
    k_wt<<<dim3(64, 64), 256, 0, stream>>>(wv, wvT, 1.f);
    k_cvt<<<4096, 256, 0, stream>>>(wo, wob, 4194304, 1.f);

    dim3 gg(32, 16);
    k_gemm_bt<0><<<gg, 256, 0, stream>>>(xb, wqT, Qb, nullptr, 4096, 2048, 2048);
    k_gemm_bt<0><<<gg, 256, 0, stream>>>(xb, wkT, Kb, nullptr, 4096, 2048, 2048);
    k_gemm_bt<0><<<gg, 256, 0, stream>>>(xb, wvT, Vb, nullptr, 4096, 2048, 2048);
    k_vtrans<<<dim3(64, 32), 256, 0, stream>>>((const unsigned short*)Vb,
                                               (unsigned short*)Vtb);
    k_attn<<<dim3(16, 16, 2), 256, 0, stream>>>(Qb, Kb, Vtb, AOb);
    k_gemm_bt<1><<<gg, 256, 0, stream>>>(AOb, wob, nullptr, out, 4096, 2048, 2048);

    // decode
    k_gemv<<<dim3(8, 2), 256, 0, stream>>>(xnb, wqT, q1b, nullptr, 2048);
    k_gemv<<<dim3(8, 2), 256, 0, stream>>>(xnb, wkT, k1b, nullptr, 2048);
    k_gemv<<<dim3(8, 2), 256, 0, stream>>>(xnb, wvT, v1b, nullptr, 2048);
    k_decode_attn<<<dim3(16, 2), 256, 0, stream>>>(Kb, Vtb, q1b, k1b, v1b, o1b);
    k_gemv<<<dim3(8, 2), 256, 0, stream>>>(o1b, wob, nullptr, out + 8388608, 2048);
}

// Round 3
// 482.055 us; speedup vs baseline: 1.6121x; 1.5289x over previous
//
#include <hip/hip_runtime.h>
#include <cmath>

typedef __bf16 bf16;
typedef short bf16x8 __attribute__((ext_vector_type(8)));   // MFMA A/B fragment (bf16 bit patterns)
typedef __bf16 bf16v8 __attribute__((ext_vector_type(8)));  // arithmetic bf16 vector
typedef __bf16 bf16v4 __attribute__((ext_vector_type(4)));
typedef float f32x4 __attribute__((ext_vector_type(4)));
typedef unsigned short u16x8 __attribute__((ext_vector_type(8)));

// async global->LDS, 16B per lane. LDS base must be wave-uniform; HW adds lane*16.
__device__ __forceinline__ void load_lds16(const void* g, void* l) {
    __builtin_amdgcn_global_load_lds(
        (const __attribute__((address_space(1))) void*)g,
        (__attribute__((address_space(3))) void*)l, 16, 0, 0);
}

// ---------------------------------------------------------------------------
// fp32 -> bf16 elementwise convert (optionally scaled). n multiple of 4.
__global__ void k_cvt(const float* __restrict__ in, bf16* __restrict__ out,
                      int n, float scale) {
    int i = (blockIdx.x * 256 + threadIdx.x) * 4;
    if (i >= n) return;
    float4 v = *(const float4*)(in + i);
    bf16v4 o;
    o[0] = (bf16)(v.x * scale);
    o[1] = (bf16)(v.y * scale);
    o[2] = (bf16)(v.z * scale);
    o[3] = (bf16)(v.w * scale);
    *(bf16v4*)(out + i) = o;
}

// ---------------------------------------------------------------------------
// Weight convert + transpose: w[K=2048][N=2048] f32 -> wt[N][K] bf16 (scaled).
__global__ void k_wt(const float* __restrict__ w, bf16* __restrict__ wt, float scale) {
    __shared__ float tile[32][33];
    const int tid = threadIdx.x;
    const int tx = tid & 31, ty = tid >> 5;  // 32 x 8
    const int k0 = blockIdx.x * 32, n0 = blockIdx.y * 32;
#pragma unroll
    for (int i = 0; i < 4; i++) {
        int kk = ty + i * 8;
        tile[kk][tx] = w[(size_t)(k0 + kk) * 2048 + n0 + tx];
    }
    __syncthreads();
#pragma unroll
    for (int i = 0; i < 4; i++) {
        int nn = ty + i * 8;
        wt[(size_t)(n0 + nn) * 2048 + k0 + tx] = (bf16)(tile[tx][nn] * scale);
    }
}

// ---------------------------------------------------------------------------
// bf16 GEMM: C[M][N] = A[M][K] * Bt[N][K]^T.  128x128 tile, 4 waves (2x2),
// each wave 64x64 via 4x4 grid of 16x16x32 MFMA tiles. BK=32.
template <int F32OUT>
__global__ __launch_bounds__(256) void k_gemm_bt(
    const bf16* __restrict__ A, const bf16* __restrict__ Bt,
    bf16* __restrict__ Cb, float* __restrict__ Cf, int M, int N, int K) {
    __shared__ __align__(16) bf16 sA[128 * 32];
    __shared__ __align__(16) bf16 sB[128 * 32];
    const int tid = threadIdx.x;
    const int wave = tid >> 6, lane = tid & 63;
    const int quad = lane >> 4, l15 = lane & 15;
    const int wm = (wave >> 1) * 64, wn = (wave & 1) * 64;
    const int m0 = blockIdx.x * 128, n0 = blockIdx.y * 128;

    f32x4 acc[4][4];
#pragma unroll
    for (int a = 0; a < 4; a++)
#pragma unroll
        for (int c = 0; c < 4; c++)
#pragma unroll
            for (int r = 0; r < 4; r++) acc[a][c][r] = 0.f;

    for (int k0 = 0; k0 < K; k0 += 32) {
        __syncthreads();
#pragma unroll
        for (int i = 0; i < 2; i++) {
            const int slotBase = wave * 128 + i * 64;  // wave-uniform
            const int slot = slotBase + lane;
            const int row = slot >> 2, kc = slot & 3;
            load_lds16(A + (size_t)(m0 + row) * K + k0 + kc * 8, &sA[slotBase * 8]);
            load_lds16(Bt + (size_t)(n0 + row) * K + k0 + kc * 8, &sB[slotBase * 8]);
        }
        __syncthreads();
        bf16x8 af[4], bfr[4];
#pragma unroll
        for (int t = 0; t < 4; t++) {
            af[t] = *(const bf16x8*)(sA + (wm + t * 16 + l15) * 32 + quad * 8);
            bfr[t] = *(const bf16x8*)(sB + (wn + t * 16 + l15) * 32 + quad * 8);
        }
#pragma unroll
        for (int mi = 0; mi < 4; mi++)
#pragma unroll
            for (int ni = 0; ni < 4; ni++)
                acc[mi][ni] = __builtin_amdgcn_mfma_f32_16x16x32_bf16(
                    af[mi], bfr[ni], acc[mi][ni], 0, 0, 0);
    }
#pragma unroll
    for (int mi = 0; mi < 4; mi++)
#pragma unroll
        for (int ni = 0; ni < 4; ni++)
#pragma unroll
            for (int r = 0; r < 4; r++) {
                int row = m0 + wm + mi * 16 + quad * 4 + r;
                int col = n0 + wn + ni * 16 + l15;
                if (F32OUT)
                    Cf[(size_t)row * N + col] = acc[mi][ni][r];
                else
                    Cb[(size_t)row * N + col] = (bf16)acc[mi][ni][r];
            }
}

// ---------------------------------------------------------------------------
// V [4096][2048] (row = b*2048+s, col = head*128+h) -> Vt[b][head][h][s]
__global__ void k_vtrans(const unsigned short* __restrict__ V,
                         unsigned short* __restrict__ Vt) {
    __shared__ __align__(16) unsigned short tile[64 * 72];
    const int tid = threadIdx.x;
    const int m0 = blockIdx.x * 64;  // s-dim (with b folded)
    const int n0 = blockIdx.y * 64;  // nh-dim
    const int r8 = tid >> 3, c8 = (tid & 7) * 8;
#pragma unroll
    for (int i = 0; i < 2; i++) {
        int row = r8 + i * 32;
        *(uint4*)(tile + row * 72 + c8) =
            *(const uint4*)(V + (size_t)(m0 + row) * 2048 + n0 + c8);
    }
    __syncthreads();
    const int b = m0 >> 11, s0 = m0 & 2047;
#pragma unroll
    for (int i = 0; i < 2; i++) {
        int nl = r8 + i * 32;
        int nh = n0 + nl;
        u16x8 o;
#pragma unroll
        for (int j = 0; j < 8; j++) o[j] = tile[(c8 + j) * 72 + nl];
        *(u16x8*)(Vt + (size_t)(b * 2048 + nh) * 2048 + s0 + c8) = o;
    }
}

// ---------------------------------------------------------------------------
// Flash-style causal prefill attention, v3.
// 512 threads = 8 waves; 128-query tile per block; 128-key iterations.
// Blocks pair q-tiles bx and 15-bx -> exactly 17 iterations each; 256 blocks
// = 1/CU, 8 waves/CU = 2/SIMD. LDS 64 KB: sK 32K + sV 32K; P reuses sK
// (barrier after last K-frag read). XOR-swizzled chunks, conflict-lean reads.
// Masking only on the diagonal tile (kt == nkt-1).
__global__ __launch_bounds__(512, 2) void k_attn(
    const bf16* __restrict__ Q, const bf16* __restrict__ Kc,
    const bf16* __restrict__ Vt, bf16* __restrict__ O) {
    __shared__ __align__(16) bf16 sK[128 * 128];
    __shared__ __align__(16) bf16 sV[128 * 128];
    const int tid = threadIdx.x;
    const int wave = tid >> 6, lane = tid & 63;
    const int quad = lane >> 4, l15 = lane & 15;
    const int head = blockIdx.y, b = blockIdx.z;
    const bf16* Kbase = Kc + (size_t)(b * 2048) * 2048 + head * 128;
    const bf16* Vbase = Vt + (size_t)(b * 2048 + head * 128) * 2048;
    bf16* sP = sK + wave * 16 * 128;  // per-wave 16 rows, reuses sK
    const int swz = l15 & 7;

    for (int phase = 0; phase < 2; ++phase) {
        const int T = phase ? (15 - blockIdx.x) : blockIdx.x;  // 128-query tile
        const int qb = T * 128;
        const int nkt = T + 1;

        const bf16* Qrow = Q + (size_t)(b * 2048 + qb + wave * 16 + l15) * 2048 + head * 128;
        bf16x8 qf[4];
#pragma unroll
        for (int kc = 0; kc < 4; kc++) qf[kc] = *(const bf16x8*)(Qrow + kc * 32 + quad * 8);

        f32x4 accO[8];
#pragma unroll
        for (int hn = 0; hn < 8; hn++)
#pragma unroll
            for (int r = 0; r < 4; r++) accO[hn][r] = 0.f;
        float m_i[4], l_i[4];
#pragma unroll
        for (int r = 0; r < 4; r++) { m_i[r] = -INFINITY; l_i[r] = 0.f; }
        const int qg_base = qb + wave * 16 + quad * 4;

        for (int kt = 0; kt < nkt; ++kt) {
            const int t0 = kt * 128;
            __syncthreads();  // prev iter's PV reads (sK-as-P, sV) done
            // stage K (128 keys x 128 h) and V (128 h x 128 s), XOR-swizzled
#pragma unroll
            for (int i = 0; i < 4; ++i) {
                const int slotBase = wave * 256 + i * 64;  // wave-uniform
                const int slot = slotBase + lane;
                const int rw = slot >> 4, cp = slot & 15;
                const int c = cp ^ (rw & 7);
                load_lds16(Kbase + (size_t)(t0 + rw) * 2048 + c * 8, &sK[slotBase * 8]);
                load_lds16(Vbase + (size_t)rw * 2048 + t0 + c * 8, &sV[slotBase * 8]);
            }
            __syncthreads();  // staging complete

            // S = Q K^T : 16 q-rows x 128 keys per wave
            f32x4 sc[8];
#pragma unroll
            for (int nt = 0; nt < 8; nt++) {
#pragma unroll
                for (int r = 0; r < 4; r++) sc[nt][r] = 0.f;
#pragma unroll
                for (int kc = 0; kc < 4; kc++) {
                    bf16x8 kf = *(const bf16x8*)(
                        sK + (nt * 16 + l15) * 128 + ((kc * 4 + quad) ^ swz) * 8);
                    sc[nt] = __builtin_amdgcn_mfma_f32_16x16x32_bf16(qf[kc], kf, sc[nt], 0, 0, 0);
                }
            }

            // online softmax (exp2 domain); mask only on diagonal tile
            const bool diag = (kt == nkt - 1);
#pragma unroll
            for (int r = 0; r < 4; r++) {
                float mt = -INFINITY;
                if (diag) {
                    const int qg = qg_base + r;
#pragma unroll
                    for (int nt = 0; nt < 8; nt++) {
                        int key = t0 + nt * 16 + l15;
                        float v = sc[nt][r];
                        if (key > qg) v = -INFINITY;
                        sc[nt][r] = v;
                        mt = fmaxf(mt, v);
                    }
                } else {
#pragma unroll
                    for (int nt = 0; nt < 8; nt++) mt = fmaxf(mt, sc[nt][r]);
                }
#pragma unroll
                for (int off = 1; off <= 8; off <<= 1) mt = fmaxf(mt, __shfl_xor(mt, off));
                float mn = fmaxf(m_i[r], mt);
                float alpha = __builtin_amdgcn_exp2f(m_i[r] - mn);
                m_i[r] = mn;
                float rs = 0.f;
#pragma unroll
                for (int nt = 0; nt < 8; nt++) {
                    float p = __builtin_amdgcn_exp2f(sc[nt][r] - mn);
                    sc[nt][r] = p;
                    rs += p;
                }
                l_i[r] = l_i[r] * alpha + rs;  // per-lane partial
#pragma unroll
                for (int hn = 0; hn < 8; hn++) accO[hn][r] *= alpha;
            }

            __syncthreads();  // all waves done reading sK as K-frags

            // P: C-layout -> per-wave region of sK (XOR swizzle) -> A-layout
#pragma unroll
            for (int nt = 0; nt < 8; nt++)
#pragma unroll
                for (int r = 0; r < 4; r++) {
                    const int prow = quad * 4 + r;
                    sP[prow * 128 + ((2 * nt + (l15 >> 3)) ^ (prow & 7)) * 8 + (l15 & 7)] =
                        (bf16)sc[nt][r];
                }

            // O += P V
#pragma unroll
            for (int kc = 0; kc < 4; kc++) {
                bf16x8 pf = *(const bf16x8*)(
                    sP + l15 * 128 + ((kc * 4 + quad) ^ swz) * 8);
#pragma unroll
                for (int hn = 0; hn < 8; hn++) {
                    bf16x8 vf = *(const bf16x8*)(
                        sV + (hn * 16 + l15) * 128 + ((kc * 4 + quad) ^ swz) * 8);
                    accO[hn] = __builtin_amdgcn_mfma_f32_16x16x32_bf16(pf, vf, accO[hn], 0, 0, 0);
                }
            }
        }

        // reduce l partials across the 16-lane row group, then write O
        float inv[4];
#pragma unroll
        for (int r = 0; r < 4; r++) {
            float l = l_i[r];
#pragma unroll
            for (int off = 1; off <= 8; off <<= 1) l += __shfl_xor(l, off);
            inv[r] = 1.f / l;
        }
        bf16* Orow = O + (size_t)(b * 2048 + qb + wave * 16) * 2048 + head * 128;
#pragma unroll
        for (int hn = 0; hn < 8; hn++)
#pragma unroll
            for (int r = 0; r < 4; r++)
                Orow[(size_t)(quad * 4 + r) * 2048 + hn * 16 + l15] =
                    (bf16)(accO[hn][r] * inv[r]);
    }
}

// ---------------------------------------------------------------------------
// Decode fused QKV GEMV: one wave per output row. grid (512, B, 3), 256 thr.
__global__ void k_gemv_qkv(const bf16* __restrict__ x,
                           const bf16* __restrict__ w0, const bf16* __restrict__ w1,
                           const bf16* __restrict__ w2,
                           bf16* __restrict__ y0, bf16* __restrict__ y1,
                           bf16* __restrict__ y2) {
    const int wave = threadIdx.x >> 6, lane = threadIdx.x & 63;
    const int n = blockIdx.x * 4 + wave;
    const int b = blockIdx.y;
    const bf16* W = blockIdx.z == 0 ? w0 : blockIdx.z == 1 ? w1 : w2;
    bf16* y = blockIdx.z == 0 ? y0 : blockIdx.z == 1 ? y1 : y2;
    const bf16* xr = x + (size_t)b * 2048;
    const bf16* wr = W + (size_t)n * 2048;
    float s = 0.f;
#pragma unroll
    for (int i = 0; i < 4; i++) {
        int k = i * 512 + lane * 8;
        bf16v8 xv = *(const bf16v8*)(xr + k);
        bf16v8 wv = *(const bf16v8*)(wr + k);
#pragma unroll
        for (int j = 0; j < 8; j++) s += (float)xv[j] * (float)wv[j];
    }
#pragma unroll
    for (int off = 1; off <= 32; off <<= 1) s += __shfl_xor(s, off);
    if (lane == 0) y[(size_t)b * 2048 + n] = (bf16)s;
}

// Final decode output GEMV (fp32 out): grid (512, B), 256 thr.
__global__ void k_gemv_o(const bf16* __restrict__ x, const bf16* __restrict__ W,
                         float* __restrict__ y) {
    const int wave = threadIdx.x >> 6, lane = threadIdx.x & 63;
    const int n = blockIdx.x * 4 + wave;
    const int b = blockIdx.y;
    const bf16* xr = x + (size_t)b * 2048;
    const bf16* wr = W + (size_t)n * 2048;
    float s = 0.f;
#pragma unroll
    for (int i = 0; i < 4; i++) {
        int k = i * 512 + lane * 8;
        bf16v8 xv = *(const bf16v8*)(xr + k);
        bf16v8 wv = *(const bf16v8*)(wr + k);
#pragma unroll
        for (int j = 0; j < 8; j++) s += (float)xv[j] * (float)wv[j];
    }
#pragma unroll
    for (int off = 1; off <= 32; off <<= 1) s += __shfl_xor(s, off);
    if (lane == 0) y[(size_t)b * 2048 + n] = s;
}

// ---------------------------------------------------------------------------
// Split-K decode attention, phase 1: grid (16 heads, 2 b, 8 splits), 256 thr.
// Each block: 256 keys; writes local max m, local sumexp l, unnormalized
// weighted V accumulation acc[128].
__global__ __launch_bounds__(256) void k_dec1(
    const bf16* __restrict__ Kc, const bf16* __restrict__ Vt,
    const bf16* __restrict__ q1, float* __restrict__ pm,
    float* __restrict__ pl, float* __restrict__ pacc) {
    __shared__ __align__(16) bf16 sq[128];
    __shared__ float sc[256];
    __shared__ float red[4];
    __shared__ float ph[256];
    const int tid = threadIdx.x;
    const int head = blockIdx.x, b = blockIdx.y, sp = blockIdx.z;
    const int s0 = sp * 256;
    const int lane = tid & 63, wave = tid >> 6;
    const int idx = (b * 16 + head) * 8 + sp;

    if (tid < 16)
        *(uint4*)(sq + tid * 8) = *(const uint4*)(q1 + (size_t)b * 2048 + head * 128 + tid * 8);
    __syncthreads();

    // scores for 256 keys
    const bf16* kr = Kc + (size_t)(b * 2048 + s0 + tid) * 2048 + head * 128;
    float s = 0.f;
#pragma unroll
    for (int k = 0; k < 128; k += 8) {
        bf16v8 kv = *(const bf16v8*)(kr + k);
        bf16v8 qv = *(const bf16v8*)(sq + k);
#pragma unroll
        for (int j = 0; j < 8; j++) s += (float)qv[j] * (float)kv[j];
    }
    // block max
    float m = s;
#pragma unroll
    for (int off = 1; off <= 32; off <<= 1) m = fmaxf(m, __shfl_xor(m, off));
    if (lane == 0) red[wave] = m;
    __syncthreads();
    const float gm = fmaxf(fmaxf(red[0], red[1]), fmaxf(red[2], red[3]));
    float p = __builtin_amdgcn_exp2f(s - gm);
    sc[tid] = p;
    float ls = p;
#pragma unroll
    for (int off = 1; off <= 32; off <<= 1) ls += __shfl_xor(ls, off);
    __syncthreads();  // red reuse + sc visibility
    if (lane == 0) red[wave] = ls;
    __syncthreads();
    if (tid == 0) {
        pm[idx] = gm;
        pl[idx] = red[0] + red[1] + red[2] + red[3];
    }

    // weighted V: thread h accumulates half the keys
    const int h = tid & 127, half = tid >> 7;
    const bf16* vr = Vt + (size_t)(b * 2048 + head * 128 + h) * 2048 + s0 + half * 128;
    float acc = 0.f;
#pragma unroll
    for (int t = 0; t < 128; t += 8) {
        bf16v8 vv = *(const bf16v8*)(vr + t);
#pragma unroll
        for (int j = 0; j < 8; j++) acc += sc[half * 128 + t + j] * (float)vv[j];
    }
    ph[tid] = acc;
    __syncthreads();
    if (half == 0) pacc[(size_t)idx * 128 + h] = ph[tid] + ph[tid + 128];
}

// Phase 2: combine 8 splits + the new token. grid (16, 2), 128 threads.
__global__ void k_dec2(const float* __restrict__ pm, const float* __restrict__ pl,
                       const float* __restrict__ pacc, const bf16* __restrict__ q1,
                       const bf16* __restrict__ k1, const bf16* __restrict__ v1,
                       bf16* __restrict__ o1) {
    __shared__ float sdot[128];
    const int tid = threadIdx.x;
    const int head = blockIdx.x, b = blockIdx.y;
    const size_t off = (size_t)b * 2048 + head * 128;
    // s_new = dot(q1, k1)
    sdot[tid] = (float)q1[off + tid] * (float)k1[off + tid];
    __syncthreads();
#pragma unroll
    for (int step = 64; step >= 1; step >>= 1) {
        if (tid < step) sdot[tid] += sdot[tid + step];
        __syncthreads();
    }
    const float sn = sdot[0];
    const int base = (b * 16 + head) * 8;
    float M = sn;
#pragma unroll
    for (int sp = 0; sp < 8; sp++) M = fmaxf(M, pm[base + sp]);
    float wn = __builtin_amdgcn_exp2f(sn - M);
    float l = wn;
    float o = wn * (float)v1[off + tid];
#pragma unroll
    for (int sp = 0; sp < 8; sp++) {
        float w = __builtin_amdgcn_exp2f(pm[base + sp] - M);
        l += pl[base + sp] * w;
        o += pacc[(size_t)(base + sp) * 128 + tid] * w;
    }
    o1[off + tid] = (bf16)(o / l);
}

// ---------------------------------------------------------------------------
extern "C" void kernel_launch(void* const* d_in, const int* in_sizes, int n_in,
                              void* d_out, int out_size, void* d_ws, size_t ws_size,
                              hipStream_t stream) {
    const float* x  = (const float*)d_in[0];   // [2,2048,2048]
    const float* xn = (const float*)d_in[1];   // [2,1,2048]
    const float* wq = (const float*)d_in[2];   // [2048,16,128]
    const float* wk = (const float*)d_in[3];
    const float* wv = (const float*)d_in[4];
    const float* wo = (const float*)d_in[5];
    float* out = (float*)d_out;

    char* p = (char*)d_ws;
    auto alloc = [&](size_t bytes) {
        char* r = p;
        p += (bytes + 255) & ~(size_t)255;
        return r;
    };
    bf16* xb  = (bf16*)alloc((size_t)4096 * 2048 * 2);
    bf16* xnb = (bf16*)alloc((size_t)2 * 2048 * 2);
    bf16* wqT = (bf16*)alloc((size_t)2048 * 2048 * 2);
    bf16* wkT = (bf16*)alloc((size_t)2048 * 2048 * 2);
    bf16* wvT = (bf16*)alloc((size_t)2048 * 2048 * 2);
    bf16* wob = (bf16*)alloc((size_t)2048 * 2048 * 2);
    bf16* Qb  = (bf16*)alloc((size_t)4096 * 2048 * 2);
    bf16* Kb  = (bf16*)alloc((size_t)4096 * 2048 * 2);
    bf16* Vb  = (bf16*)alloc((size_t)4096 * 2048 * 2);
    bf16* Vtb = (bf16*)alloc((size_t)4096 * 2048 * 2);
    bf16* AOb = (bf16*)alloc((size_t)4096 * 2048 * 2);
    bf16* q1b = (bf16*)alloc((size_t)2 * 2048 * 2);
    bf16* k1b = (bf16*)alloc((size_t)2 * 2048 * 2);
    bf16* v1b = (bf16*)alloc((size_t)2 * 2048 * 2);
    bf16* o1b = (bf16*)alloc((size_t)2 * 2048 * 2);
    float* pm   = (float*)alloc(256 * 4);
    float* pl   = (float*)alloc(256 * 4);
    float* pacc = (float*)alloc((size_t)256 * 128 * 4);

    // 1/sqrt(128) * log2(e): softmax runs in exp2 domain
    const float qscale = 0.08838834764831845f * 1.4426950408889634f;

    k_cvt<<<8192, 256, 0, stream>>>(x, xb, 8388608, 1.f);
    k_cvt<<<4, 256, 0, stream>>>(xn, xnb, 4096, 1.f);
    k_wt<<<dim3(64, 64), 256, 0, stream>>>(wq, wqT, qscale);
    k_wt<<<dim3(64, 64), 256, 0, stream>>>(wk, wkT, 1.f);
    k_wt<<<dim3(64, 64), 256, 0, stream>>>(wv, wvT, 1.f);
    k_cvt<<<4096, 256, 0, stream>>>(wo, wob, 4194304, 1.f);

    dim3 gg(32, 16);
    k_gemm_bt<0><<<gg, 256, 0, stream>>>(xb, wqT, Qb, nullptr, 4096, 2048, 2048);
    k_gemm_bt<0><<<gg, 256, 0, stream>>>(xb, wkT, Kb, nullptr, 4096, 2048, 2048);
    k_gemm_bt<0><<<gg, 256, 0, stream>>>(xb, wvT, Vb, nullptr, 4096, 2048, 2048);
    k_vtrans<<<dim3(64, 32), 256, 0, stream>>>((const unsigned short*)Vb,
                                               (unsigned short*)Vtb);
    k_attn<<<dim3(8, 16, 2), 512, 0, stream>>>(Qb, Kb, Vtb, AOb);
    k_gemm_bt<1><<<gg, 256, 0, stream>>>(AOb, wob, nullptr, out, 4096, 2048, 2048);

    // decode
    k_gemv_qkv<<<dim3(512, 2, 3), 256, 0, stream>>>(xnb, wqT, wkT, wvT, q1b, k1b, v1b);
    k_dec1<<<dim3(16, 2, 8), 256, 0, stream>>>(Kb, Vtb, q1b, pm, pl, pacc);
    k_dec2<<<dim3(16, 2), 128, 0, stream>>>(pm, pl, pacc, q1b, k1b, v1b, o1b);
    k_gemv_o<<<dim3(512, 2), 256, 0, stream>>>(o1b, wob, out + 8388608);
}

// Round 5
// 441.407 us; speedup vs baseline: 1.7606x; 1.0921x over previous
//
#include <hip/hip_runtime.h>
#include <cmath>

typedef __bf16 bf16;
typedef short bf16x8 __attribute__((ext_vector_type(8)));   // MFMA A/B fragment (bf16 bit patterns)
typedef __bf16 bf16v8 __attribute__((ext_vector_type(8)));  // arithmetic bf16 vector
typedef __bf16 bf16v4 __attribute__((ext_vector_type(4)));
typedef float f32x4 __attribute__((ext_vector_type(4)));
typedef float f32x16 __attribute__((ext_vector_type(16)));

// async global->LDS, 16B per lane. LDS base must be wave-uniform; HW adds lane*16.
__device__ __forceinline__ void load_lds16(const void* g, void* l) {
    __builtin_amdgcn_global_load_lds(
        (const __attribute__((address_space(1))) void*)g,
        (__attribute__((address_space(3))) void*)l, 16, 0, 0);
}

__device__ __forceinline__ unsigned pack_bf16x2(float a, float b) {
    union { bf16 h[2]; unsigned u; } t;
    t.h[0] = (bf16)a;
    t.h[1] = (bf16)b;
    return t.u;
}

// ---------------------------------------------------------------------------
// fp32 -> bf16 elementwise convert (optionally scaled). n multiple of 4.
__global__ void k_cvt(const float* __restrict__ in, bf16* __restrict__ out,
                      int n, float scale) {
    int i = (blockIdx.x * 256 + threadIdx.x) * 4;
    if (i >= n) return;
    float4 v = *(const float4*)(in + i);
    bf16v4 o;
    o[0] = (bf16)(v.x * scale);
    o[1] = (bf16)(v.y * scale);
    o[2] = (bf16)(v.z * scale);
    o[3] = (bf16)(v.w * scale);
    *(bf16v4*)(out + i) = o;
}

// ---------------------------------------------------------------------------
// Weight convert + transpose (3 weights in one launch, grid.z selects):
// w[K=2048][N=2048] f32 -> wt[N][K] bf16 (scaled).
__global__ void k_wt3(const float* __restrict__ wq, const float* __restrict__ wk,
                      const float* __restrict__ wv, bf16* __restrict__ wqT,
                      bf16* __restrict__ wkT, bf16* __restrict__ wvT, float qscale) {
    __shared__ float tile[32][33];
    const int z = blockIdx.z;
    const float* w = z == 0 ? wq : z == 1 ? wk : wv;
    bf16* wt = z == 0 ? wqT : z == 1 ? wkT : wvT;
    const float scale = z == 0 ? qscale : 1.f;
    const int tid = threadIdx.x;
    const int tx = tid & 31, ty = tid >> 5;  // 32 x 8
    const int k0 = blockIdx.x * 32, n0 = blockIdx.y * 32;
#pragma unroll
    for (int i = 0; i < 4; i++) {
        int kk = ty + i * 8;
        tile[kk][tx] = w[(size_t)(k0 + kk) * 2048 + n0 + tx];
    }
    __syncthreads();
#pragma unroll
    for (int i = 0; i < 4; i++) {
        int nn = ty + i * 8;
        wt[(size_t)(n0 + nn) * 2048 + k0 + tx] = (bf16)(tile[tx][nn] * scale);
    }
}

// ---------------------------------------------------------------------------
// bf16 GEMM (wo projection): C[M][N] = A[M][K] * Bt[N][K]^T, f32 out.
// 128x128 tile, 4 waves (2x2), 4x4 of 16x16x32 MFMA per wave. BK=32.
__global__ __launch_bounds__(256) void k_gemm_o(
    const bf16* __restrict__ A, const bf16* __restrict__ Bt,
    float* __restrict__ Cf, int M, int N, int K) {
    __shared__ __align__(16) bf16 sA[128 * 32];
    __shared__ __align__(16) bf16 sB[128 * 32];
    const int tid = threadIdx.x;
    const int wave = tid >> 6, lane = tid & 63;
    const int quad = lane >> 4, l15 = lane & 15;
    const int wm = (wave >> 1) * 64, wn = (wave & 1) * 64;
    const int m0 = blockIdx.x * 128, n0 = blockIdx.y * 128;

    f32x4 acc[4][4];
#pragma unroll
    for (int a = 0; a < 4; a++)
#pragma unroll
        for (int c = 0; c < 4; c++)
#pragma unroll
            for (int r = 0; r < 4; r++) acc[a][c][r] = 0.f;

    for (int k0 = 0; k0 < K; k0 += 32) {
        __syncthreads();
#pragma unroll
        for (int i = 0; i < 2; i++) {
            const int slotBase = wave * 128 + i * 64;  // wave-uniform
            const int slot = slotBase + lane;
            const int row = slot >> 2, kc = slot & 3;
            load_lds16(A + (size_t)(m0 + row) * K + k0 + kc * 8, &sA[slotBase * 8]);
            load_lds16(Bt + (size_t)(n0 + row) * K + k0 + kc * 8, &sB[slotBase * 8]);
        }
        __syncthreads();
        bf16x8 af[4], bfr[4];
#pragma unroll
        for (int t = 0; t < 4; t++) {
            af[t] = *(const bf16x8*)(sA + (wm + t * 16 + l15) * 32 + quad * 8);
            bfr[t] = *(const bf16x8*)(sB + (wn + t * 16 + l15) * 32 + quad * 8);
        }
#pragma unroll
        for (int mi = 0; mi < 4; mi++)
#pragma unroll
            for (int ni = 0; ni < 4; ni++)
                acc[mi][ni] = __builtin_amdgcn_mfma_f32_16x16x32_bf16(
                    af[mi], bfr[ni], acc[mi][ni], 0, 0, 0);
    }
#pragma unroll
    for (int mi = 0; mi < 4; mi++)
#pragma unroll
        for (int ni = 0; ni < 4; ni++)
#pragma unroll
            for (int r = 0; r < 4; r++) {
                int row = m0 + wm + mi * 16 + quad * 4 + r;
                int col = n0 + wn + ni * 16 + l15;
                Cf[(size_t)row * N + col] = acc[mi][ni][r];
            }
}

// ---------------------------------------------------------------------------
// Fused QKV GEMM: A[4096][2048] x Bt[6144][2048]^T. Bt = [wqT; wkT; wvT]
// (contiguous). n0<2048 -> Q normal; <4096 -> K normal; else V written
// TRANSPOSED into Vt[b][nh][s] (packed 8B stores).
__global__ __launch_bounds__(256) void k_gemm_qkv(
    const bf16* __restrict__ A, const bf16* __restrict__ Bt,
    bf16* __restrict__ Qo, bf16* __restrict__ Ko, bf16* __restrict__ Vto) {
    const int K = 2048;
    __shared__ __align__(16) bf16 sA[128 * 32];
    __shared__ __align__(16) bf16 sB[128 * 32];
    const int tid = threadIdx.x;
    const int wave = tid >> 6, lane = tid & 63;
    const int quad = lane >> 4, l15 = lane & 15;
    const int wm = (wave >> 1) * 64, wn = (wave & 1) * 64;
    const int m0 = blockIdx.x * 128, n0 = blockIdx.y * 128;

    f32x4 acc[4][4];
#pragma unroll
    for (int a = 0; a < 4; a++)
#pragma unroll
        for (int c = 0; c < 4; c++)
#pragma unroll
            for (int r = 0; r < 4; r++) acc[a][c][r] = 0.f;

    for (int k0 = 0; k0 < K; k0 += 32) {
        __syncthreads();
#pragma unroll
        for (int i = 0; i < 2; i++) {
            const int slotBase = wave * 128 + i * 64;
            const int slot = slotBase + lane;
            const int row = slot >> 2, kc = slot & 3;
            load_lds16(A + (size_t)(m0 + row) * K + k0 + kc * 8, &sA[slotBase * 8]);
            load_lds16(Bt + (size_t)(n0 + row) * K + k0 + kc * 8, &sB[slotBase * 8]);
        }
        __syncthreads();
        bf16x8 af[4], bfr[4];
#pragma unroll
        for (int t = 0; t < 4; t++) {
            af[t] = *(const bf16x8*)(sA + (wm + t * 16 + l15) * 32 + quad * 8);
            bfr[t] = *(const bf16x8*)(sB + (wn + t * 16 + l15) * 32 + quad * 8);
        }
#pragma unroll
        for (int mi = 0; mi < 4; mi++)
#pragma unroll
            for (int ni = 0; ni < 4; ni++)
                acc[mi][ni] = __builtin_amdgcn_mfma_f32_16x16x32_bf16(
                    af[mi], bfr[ni], acc[mi][ni], 0, 0, 0);
    }

    if (n0 < 4096) {
        bf16* Co = n0 < 2048 ? Qo : Ko;
        const int nb = n0 & 2047;
#pragma unroll
        for (int mi = 0; mi < 4; mi++)
#pragma unroll
            for (int ni = 0; ni < 4; ni++)
#pragma unroll
                for (int r = 0; r < 4; r++) {
                    int row = m0 + wm + mi * 16 + quad * 4 + r;
                    int col = nb + wn + ni * 16 + l15;
                    Co[(size_t)row * 2048 + col] = (bf16)acc[mi][ni][r];
                }
    } else {
        const int nb = n0 - 4096;
        const int b = m0 >> 11, s0v = m0 & 2047;
#pragma unroll
        for (int mi = 0; mi < 4; mi++)
#pragma unroll
            for (int ni = 0; ni < 4; ni++) {
                const int nh = nb + wn + ni * 16 + l15;
                bf16v4 o4;
#pragma unroll
                for (int r = 0; r < 4; r++) o4[r] = (bf16)acc[mi][ni][r];
                *(bf16v4*)(Vto + (size_t)(b * 2048 + nh) * 2048 + s0v + wm +
                           mi * 16 + quad * 4) = o4;
            }
    }
}

// ---------------------------------------------------------------------------
// Flash-style causal prefill attention, v5 (32x32 MFMA, kappa-permuted keys).
// S^T = K Q^T with K staged in LDS under row permutation kappa(r) = swap bits
// 2<->3 of r. With that permutation, S^T's C-layout registers ARE the PV
// B-operand fragments (packed bf16 pairs) -- no shuffle, no LDS round-trip.
// V stays naturally staged; its A-frag b128 reads are unchanged (sigma = id).
// Actual key of C-slot (mt,g,half): 32*mt + 16*g3 + 8*half + 4*g2 + (g&3).
// 256 thr = 4 waves x 32 queries; 128-query tile; 128-key iterations;
// 64 KB LDS; 512 blocks (2/CU) with (T, 15-T) pairing for balance.
__global__ __launch_bounds__(256, 2) void k_attn(
    const bf16* __restrict__ Q, const bf16* __restrict__ Kc,
    const bf16* __restrict__ Vt, bf16* __restrict__ O) {
    __shared__ __align__(16) bf16 sK[128 * 128];
    __shared__ __align__(16) bf16 sV[128 * 128];
    const int tid = threadIdx.x;
    const int wave = tid >> 6, lane = tid & 63;
    const int l31 = lane & 31, half = lane >> 5;
    const int lin = blockIdx.x;
    const int bb = lin >> 8;
    const int idx = lin & 255;
    const int T = bb ? (15 - (idx & 15)) : (idx & 15);
    const int head = idx >> 4;
    const int qb = T * 128;
    const int nkt = T + 1;

    const bf16* Kbase = Kc + (size_t)(bb * 2048) * 2048 + head * 128;
    const bf16* Vbase = Vt + (size_t)(bb * 2048 + head * 128) * 2048;
    const int swzA = l31 & 7;

    // Q^T B-frags: lane holds Q[query = qb+wave*32+l31][d = kc*16 + half*8 + j]
    const int query_l = wave * 32 + l31;
    const bf16* Qrow = Q + (size_t)(bb * 2048 + qb + query_l) * 2048 + head * 128;
    bf16x8 qf[8];
#pragma unroll
    for (int kc = 0; kc < 8; kc++)
        qf[kc] = *(const bf16x8*)(Qrow + kc * 16 + half * 8);

    f32x16 accO[4];
#pragma unroll
    for (int ht = 0; ht < 4; ht++)
#pragma unroll
        for (int g = 0; g < 16; g++) accO[ht][g] = 0.f;
    float m_i = -INFINITY, l_i = 0.f;
    const int query_g = qb + query_l;

    for (int kt = 0; kt < nkt; ++kt) {
        const int t0 = kt * 128;
        __syncthreads();  // prev iter's frag reads done
#pragma unroll
        for (int i = 0; i < 8; ++i) {
            const int slotBase = wave * 512 + i * 64;  // wave-uniform
            const int slot = slotBase + lane;
            const int rw = slot >> 4, cp = slot & 15;
            const int c = cp ^ (rw & 7);
            // kappa: LDS row rw holds global key t0 + (rw with bits 2,3 swapped)
            const int krw = (rw & ~12) | ((rw & 4) << 1) | ((rw & 8) >> 1);
            load_lds16(Kbase + (size_t)(t0 + krw) * 2048 + c * 8, &sK[slotBase * 8]);
            load_lds16(Vbase + (size_t)rw * 2048 + t0 + c * 8, &sV[slotBase * 8]);
        }
        __syncthreads();  // staging complete

        // S^T: key-slots (M, 4 tiles of 32) x queries (N=32)
        f32x16 sc[4];
#pragma unroll
        for (int mt = 0; mt < 4; mt++) {
#pragma unroll
            for (int g = 0; g < 16; g++) sc[mt][g] = 0.f;
#pragma unroll
            for (int kc = 0; kc < 8; kc++) {
                bf16x8 kf = *(const bf16x8*)(
                    sK + (mt * 32 + l31) * 128 + (((kc * 2 + half) ^ swzA)) * 8);
                sc[mt] = __builtin_amdgcn_mfma_f32_32x32x16_bf16(kf, qf[kc], sc[mt], 0, 0, 0);
            }
        }

        // causal mask on diagonal tile only (kappa-aware key formula)
        if (kt == nkt - 1) {
#pragma unroll
            for (int mt = 0; mt < 4; mt++)
#pragma unroll
                for (int g = 0; g < 16; g++) {
                    int key = t0 + mt * 32 + 16 * ((g >> 3) & 1) + 8 * half +
                              4 * ((g >> 2) & 1) + (g & 3);
                    if (key > query_g) sc[mt][g] = -INFINITY;
                }
        }

        // online softmax (exp2 domain), one m/l per lane (query column)
        float mt_ = -INFINITY;
#pragma unroll
        for (int mt = 0; mt < 4; mt++)
#pragma unroll
            for (int g = 0; g < 16; g++) mt_ = fmaxf(mt_, sc[mt][g]);
        mt_ = fmaxf(mt_, __shfl_xor(mt_, 32));
        const float mn = fmaxf(m_i, mt_);
        const float alpha = __builtin_amdgcn_exp2f(m_i - mn);
        m_i = mn;
        float rs = 0.f;
#pragma unroll
        for (int mt = 0; mt < 4; mt++)
#pragma unroll
            for (int g = 0; g < 16; g++) {
                float pv = __builtin_amdgcn_exp2f(sc[mt][g] - mn);
                sc[mt][g] = pv;
                rs += pv;
            }
        l_i = l_i * alpha + rs;  // lane-partial (lane and lane^32 hold disjoint keys)
#pragma unroll
        for (int ht = 0; ht < 4; ht++)
#pragma unroll
            for (int g = 0; g < 16; g++) accO[ht][g] *= alpha;

        // pack P to bf16 pairs; with kappa staging these ARE the B-frags
        unsigned pk[4][8];
#pragma unroll
        for (int mt = 0; mt < 4; mt++)
#pragma unroll
            for (int p = 0; p < 8; p++)
                pk[mt][p] = pack_bf16x2(sc[mt][2 * p], sc[mt][2 * p + 1]);

        // PV: B-frag for chunk kc = pk[kc>>1][4*(kc&1) + 0..3], same lane
#pragma unroll
        for (int kc = 0; kc < 8; kc++) {
            union { unsigned u[4]; bf16x8 v; } pf;
            const int mtk = kc >> 1, base = 4 * (kc & 1);
#pragma unroll
            for (int jj = 0; jj < 4; jj++) pf.u[jj] = pk[mtk][base + jj];
#pragma unroll
            for (int ht = 0; ht < 4; ht++) {
                bf16x8 vf = *(const bf16x8*)(
                    sV + (ht * 32 + l31) * 128 + (((kc * 2 + half) ^ swzA)) * 8);
                accO[ht] = __builtin_amdgcn_mfma_f32_32x32x16_bf16(vf, pf.v, accO[ht], 0, 0, 0);
            }
        }
    }

    const float linv = 1.f / (l_i + __shfl_xor(l_i, 32));
    bf16* Orow = O + (size_t)(bb * 2048 + qb + query_l) * 2048 + head * 128;
#pragma unroll
    for (int ht = 0; ht < 4; ht++)
#pragma unroll
        for (int u = 0; u < 4; u++) {
            bf16v4 o4;
#pragma unroll
            for (int i = 0; i < 4; i++) o4[i] = (bf16)(accO[ht][4 * u + i] * linv);
            *(bf16v4*)(Orow + ht * 32 + 8 * u + 4 * half) = o4;
        }
}

// ---------------------------------------------------------------------------
// Decode fused QKV GEMV: one wave per output row. grid (512, B, 3), 256 thr.
__global__ void k_gemv_qkv(const bf16* __restrict__ x,
                           const bf16* __restrict__ w0, const bf16* __restrict__ w1,
                           const bf16* __restrict__ w2,
                           bf16* __restrict__ y0, bf16* __restrict__ y1,
                           bf16* __restrict__ y2) {
    const int wave = threadIdx.x >> 6, lane = threadIdx.x & 63;
    const int n = blockIdx.x * 4 + wave;
    const int b = blockIdx.y;
    const bf16* W = blockIdx.z == 0 ? w0 : blockIdx.z == 1 ? w1 : w2;
    bf16* y = blockIdx.z == 0 ? y0 : blockIdx.z == 1 ? y1 : y2;
    const bf16* xr = x + (size_t)b * 2048;
    const bf16* wr = W + (size_t)n * 2048;
    float s = 0.f;
#pragma unroll
    for (int i = 0; i < 4; i++) {
        int k = i * 512 + lane * 8;
        bf16v8 xv = *(const bf16v8*)(xr + k);
        bf16v8 wv = *(const bf16v8*)(wr + k);
#pragma unroll
        for (int j = 0; j < 8; j++) s += (float)xv[j] * (float)wv[j];
    }
#pragma unroll
    for (int off = 1; off <= 32; off <<= 1) s += __shfl_xor(s, off);
    if (lane == 0) y[(size_t)b * 2048 + n] = (bf16)s;
}

// Final decode output GEMV (fp32 out): grid (512, B), 256 thr.
__global__ void k_gemv_o(const bf16* __restrict__ x, const bf16* __restrict__ W,
                         float* __restrict__ y) {
    const int wave = threadIdx.x >> 6, lane = threadIdx.x & 63;
    const int n = blockIdx.x * 4 + wave;
    const int b = blockIdx.y;
    const bf16* xr = x + (size_t)b * 2048;
    const bf16* wr = W + (size_t)n * 2048;
    float s = 0.f;
#pragma unroll
    for (int i = 0; i < 4; i++) {
        int k = i * 512 + lane * 8;
        bf16v8 xv = *(const bf16v8*)(xr + k);
        bf16v8 wv = *(const bf16v8*)(wr + k);
#pragma unroll
        for (int j = 0; j < 8; j++) s += (float)xv[j] * (float)wv[j];
    }
#pragma unroll
    for (int off = 1; off <= 32; off <<= 1) s += __shfl_xor(s, off);
    if (lane == 0) y[(size_t)b * 2048 + n] = s;
}

// ---------------------------------------------------------------------------
// Split-K decode attention, phase 1: grid (16 heads, 2 b, 8 splits), 256 thr.
__global__ __launch_bounds__(256) void k_dec1(
    const bf16* __restrict__ Kc, const bf16* __restrict__ Vt,
    const bf16* __restrict__ q1, float* __restrict__ pm,
    float* __restrict__ pl, float* __restrict__ pacc) {
    __shared__ __align__(16) bf16 sq[128];
    __shared__ float sc[256];
    __shared__ float red[4];
    __shared__ float ph[256];
    const int tid = threadIdx.x;
    const int head = blockIdx.x, b = blockIdx.y, sp = blockIdx.z;
    const int s0 = sp * 256;
    const int lane = tid & 63, wave = tid >> 6;
    const int idx = (b * 16 + head) * 8 + sp;

    if (tid < 16)
        *(uint4*)(sq + tid * 8) = *(const uint4*)(q1 + (size_t)b * 2048 + head * 128 + tid * 8);
    __syncthreads();

    const bf16* kr = Kc + (size_t)(b * 2048 + s0 + tid) * 2048 + head * 128;
    float s = 0.f;
#pragma unroll
    for (int k = 0; k < 128; k += 8) {
        bf16v8 kv = *(const bf16v8*)(kr + k);
        bf16v8 qv = *(const bf16v8*)(sq + k);
#pragma unroll
        for (int j = 0; j < 8; j++) s += (float)qv[j] * (float)kv[j];
    }
    float m = s;
#pragma unroll
    for (int off = 1; off <= 32; off <<= 1) m = fmaxf(m, __shfl_xor(m, off));
    if (lane == 0) red[wave] = m;
    __syncthreads();
    const float gm = fmaxf(fmaxf(red[0], red[1]), fmaxf(red[2], red[3]));
    float p = __builtin_amdgcn_exp2f(s - gm);
    sc[tid] = p;
    float ls = p;
#pragma unroll
    for (int off = 1; off <= 32; off <<= 1) ls += __shfl_xor(ls, off);
    __syncthreads();
    if (lane == 0) red[wave] = ls;
    __syncthreads();
    if (tid == 0) {
        pm[idx] = gm;
        pl[idx] = red[0] + red[1] + red[2] + red[3];
    }

    const int h = tid & 127, halfk = tid >> 7;
    const bf16* vr = Vt + (size_t)(b * 2048 + head * 128 + h) * 2048 + s0 + halfk * 128;
    float acc = 0.f;
#pragma unroll
    for (int t = 0; t < 128; t += 8) {
        bf16v8 vv = *(const bf16v8*)(vr + t);
#pragma unroll
        for (int j = 0; j < 8; j++) acc += sc[halfk * 128 + t + j] * (float)vv[j];
    }
    ph[tid] = acc;
    __syncthreads();
    if (halfk == 0) pacc[(size_t)idx * 128 + h] = ph[tid] + ph[tid + 128];
}

// Phase 2: combine 8 splits + the new token. grid (16, 2), 128 threads.
__global__ void k_dec2(const float* __restrict__ pm, const float* __restrict__ pl,
                       const float* __restrict__ pacc, const bf16* __restrict__ q1,
                       const bf16* __restrict__ k1, const bf16* __restrict__ v1,
                       bf16* __restrict__ o1) {
    __shared__ float sdot[128];
    const int tid = threadIdx.x;
    const int head = blockIdx.x, b = blockIdx.y;
    const size_t off = (size_t)b * 2048 + head * 128;
    sdot[tid] = (float)q1[off + tid] * (float)k1[off + tid];
    __syncthreads();
#pragma unroll
    for (int step = 64; step >= 1; step >>= 1) {
        if (tid < step) sdot[tid] += sdot[tid + step];
        __syncthreads();
    }
    const float sn = sdot[0];
    const int base = (b * 16 + head) * 8;
    float M = sn;
#pragma unroll
    for (int sp = 0; sp < 8; sp++) M = fmaxf(M, pm[base + sp]);
    float wn = __builtin_amdgcn_exp2f(sn - M);
    float l = wn;
    float o = wn * (float)v1[off + tid];
#pragma unroll
    for (int sp = 0; sp < 8; sp++) {
        float w = __builtin_amdgcn_exp2f(pm[base + sp] - M);
        l += pl[base + sp] * w;
        o += pacc[(size_t)(base + sp) * 128 + tid] * w;
    }
    o1[off + tid] = (bf16)(o / l);
}

// ---------------------------------------------------------------------------
extern "C" void kernel_launch(void* const* d_in, const int* in_sizes, int n_in,
                              void* d_out, int out_size, void* d_ws, size_t ws_size,
                              hipStream_t stream) {
    const float* x  = (const float*)d_in[0];   // [2,2048,2048]
    const float* xn = (const float*)d_in[1];   // [2,1,2048]
    const float* wq = (const float*)d_in[2];   // [2048,16,128]
    const float* wk = (const float*)d_in[3];
    const float* wv = (const float*)d_in[4];
    const float* wo = (const float*)d_in[5];
    float* out = (float*)d_out;

    char* p = (char*)d_ws;
    auto alloc = [&](size_t bytes) {
        char* r = p;
        p += (bytes + 255) & ~(size_t)255;
        return r;
    };
    bf16* xb  = (bf16*)alloc((size_t)4096 * 2048 * 2);
    bf16* xnb = (bf16*)alloc((size_t)2 * 2048 * 2);
    // wqT, wkT, wvT MUST be contiguous (fused QKV GEMM reads them as one
    // [6144][2048] matrix). 8 MB each, 256-aligned sizes -> contiguous.
    bf16* wqT = (bf16*)alloc((size_t)2048 * 2048 * 2);
    bf16* wkT = (bf16*)alloc((size_t)2048 * 2048 * 2);
    bf16* wvT = (bf16*)alloc((size_t)2048 * 2048 * 2);
    bf16* wob = (bf16*)alloc((size_t)2048 * 2048 * 2);
    bf16* Qb  = (bf16*)alloc((size_t)4096 * 2048 * 2);
    bf16* Kb  = (bf16*)alloc((size_t)4096 * 2048 * 2);
    bf16* Vtb = (bf16*)alloc((size_t)4096 * 2048 * 2);
    bf16* AOb = (bf16*)alloc((size_t)4096 * 2048 * 2);
    bf16* q1b = (bf16*)alloc((size_t)2 * 2048 * 2);
    bf16* k1b = (bf16*)alloc((size_t)2 * 2048 * 2);
    bf16* v1b = (bf16*)alloc((size_t)2 * 2048 * 2);
    bf16* o1b = (bf16*)alloc((size_t)2 * 2048 * 2);
    float* pm   = (float*)alloc(256 * 4);
    float* pl   = (float*)alloc(256 * 4);
    float* pacc = (float*)alloc((size_t)256 * 128 * 4);

    // 1/sqrt(128) * log2(e): softmax runs in exp2 domain
    const float qscale = 0.08838834764831845f * 1.4426950408889634f;

    k_cvt<<<8192, 256, 0, stream>>>(x, xb, 8388608, 1.f);
    k_cvt<<<4, 256, 0, stream>>>(xn, xnb, 4096, 1.f);
    k_wt3<<<dim3(64, 64, 3), 256, 0, stream>>>(wq, wk, wv, wqT, wkT, wvT, qscale);
    k_cvt<<<4096, 256, 0, stream>>>(wo, wob, 4194304, 1.f);

    k_gemm_qkv<<<dim3(32, 48), 256, 0, stream>>>(xb, wqT, Qb, Kb, Vtb);
    k_attn<<<512, 256, 0, stream>>>(Qb, Kb, Vtb, AOb);
    k_gemm_o<<<dim3(32, 16), 256, 0, stream>>>(AOb, wob, out, 4096, 2048, 2048);

    // decode
    k_gemv_qkv<<<dim3(512, 2, 3), 256, 0, stream>>>(xnb, wqT, wkT, wvT, q1b, k1b, v1b);
    k_dec1<<<dim3(16, 2, 8), 256, 0, stream>>>(Kb, Vtb, q1b, pm, pl, pacc);
    k_dec2<<<dim3(16, 2), 128, 0, stream>>>(pm, pl, pacc, q1b, k1b, v1b, o1b);
    k_gemv_o<<<dim3(512, 2), 256, 0, stream>>>(o1b, wob, out + 8388608);
}